// Round 1
// baseline (914.339 us; speedup 1.0000x reference)
//
#include <hip/hip_runtime.h>
#include <hip/hip_bf16.h>
#include <stdint.h>
#include <stddef.h>

// ---- model dims ----
#define Vv   32000
#define Dd   1024
#define NLay 2
#define Ss   2048
#define Nn   16
#define Kc   4
#define DIc  2048
#define EPSf 1e-5f
#define LCH  64
#define NCHc (Ss / LCH)   // 32 chunks

typedef __attribute__((ext_vector_type(8))) short bf16x8;
typedef __attribute__((ext_vector_type(4))) float f32x4;

__device__ __forceinline__ short f2bf(float f) {
  union { float f; unsigned u; } a; a.f = f;
  return (short)((a.u + 0x7FFFu + ((a.u >> 16) & 1u)) >> 16);  // RNE
}
__device__ __forceinline__ float bf2f(short s) {
  union { unsigned u; float f; } a; a.u = ((unsigned)(unsigned short)s) << 16;
  return a.f;
}

// ---------------- f32 -> bf16 convert (vectorized) ----------------
__global__ __launch_bounds__(256) void cvt_k(const float* __restrict__ in,
                                             short* __restrict__ out, int n4) {
  int i = blockIdx.x * 256 + threadIdx.x;
  if (i < n4) {
    float4 v = ((const float4*)in)[i];
    short4 o;
    o.x = f2bf(v.x); o.y = f2bf(v.y); o.z = f2bf(v.z); o.w = f2bf(v.w);
    ((short4*)out)[i] = o;
  }
}

// ---------------- embedding gather ----------------
__global__ __launch_bounds__(256) void embed_k(const int* __restrict__ ids,
                                               const float* __restrict__ emb,
                                               float* __restrict__ x) {
  int s = blockIdx.x;
  int id = ids[s];
  const float4* src = (const float4*)(emb + (size_t)id * Dd);
  float4* dst = (float4*)(x + (size_t)s * Dd);
  dst[threadIdx.x] = src[threadIdx.x];   // 256 threads * 4 = 1024
}

// ---------------- RMSNorm -> bf16 ----------------
__global__ __launch_bounds__(256) void rmsnorm_k(const float* __restrict__ x,
                                                 const float* __restrict__ w,
                                                 short* __restrict__ o) {
  int s = blockIdx.x, t = threadIdx.x;
  float4 v = ((const float4*)(x + (size_t)s * Dd))[t];
  float ss = v.x * v.x + v.y * v.y + v.z * v.z + v.w * v.w;
#pragma unroll
  for (int off = 32; off; off >>= 1) ss += __shfl_down(ss, off);
  __shared__ float red[4];
  if ((t & 63) == 0) red[t >> 6] = ss;
  __syncthreads();
  ss = red[0] + red[1] + red[2] + red[3];
  float rinv = rsqrtf(ss * (1.0f / Dd) + EPSf);
  float4 wv = ((const float4*)w)[t];
  short4 ov;
  ov.x = f2bf(v.x * rinv * wv.x);
  ov.y = f2bf(v.y * rinv * wv.y);
  ov.z = f2bf(v.z * rinv * wv.z);
  ov.w = f2bf(v.w * rinv * wv.w);
  ((short4*)(o + (size_t)s * Dd))[t] = ov;
}

// ---------------- bf16 B^T GEMM: C[M,N] = A[M,K] * B[N,K]^T (+res) ----------------
// m97-structure: 128-wide tiles, BK=32, global_load_lds(16B) staging with an
// XOR slot-swizzle (phys16 = 4*row + (slot ^ (row&3) ^ ((row>>2)&1))) so the
// ds_read_b128 fragment reads are <=2-way bank conflicted.
template <int BM, int BN, int WM, int WN, bool RESID>
__global__ __launch_bounds__(256) void gemm_bt(const short* __restrict__ A,
                                               const short* __restrict__ B,
                                               float* C, const float* res,
                                               int M, int N, int K) {
  constexpr int BK = 32;
  constexpr int FM = BM / (WM * 16);
  constexpr int FN = BN / (WN * 16);
  constexpr int A_SLOTS = BM * (BK / 8);  // 16B slots
  constexpr int B_SLOTS = BN * (BK / 8);
  __shared__ short sA[BM * BK];
  __shared__ short sB[BN * BK];
  const int t = threadIdx.x;
  const int lane = t & 63;
  const int w = t >> 6;
  const int wm = w / WN, wn = w % WN;
  const int rowBase = blockIdx.y * BM;
  const int colBase = blockIdx.x * BN;
  const int l4 = lane >> 4;
  const int lr = lane & 15;
  const int mrd = ((lr & 3) ^ ((lr >> 2) & 1));  // swizzle mask for frag rows

  f32x4 acc[FM][FN];
#pragma unroll
  for (int i = 0; i < FM; i++)
#pragma unroll
    for (int j = 0; j < FN; j++) acc[i][j] = f32x4{0.f, 0.f, 0.f, 0.f};

  for (int k0 = 0; k0 < K; k0 += BK) {
    __syncthreads();
#pragma unroll
    for (int i = 0; i < (A_SLOTS + 255) / 256; i++) {
      int q = i * 256 + t;
      if (A_SLOTS % 256 == 0 || q < A_SLOTS) {
        int row = q >> 2, ps = q & 3;
        int ls = ps ^ ((row & 3) ^ ((row >> 2) & 1));
        const short* src = A + (size_t)(rowBase + row) * K + (k0 + ls * 8);
        __builtin_amdgcn_global_load_lds(
            (__attribute__((address_space(1))) unsigned int*)src,
            (__attribute__((address_space(3))) unsigned int*)(sA + q * 8), 16, 0, 0);
      }
    }
#pragma unroll
    for (int i = 0; i < (B_SLOTS + 255) / 256; i++) {
      int q = i * 256 + t;
      if (B_SLOTS % 256 == 0 || q < B_SLOTS) {
        int row = q >> 2, ps = q & 3;
        int ls = ps ^ ((row & 3) ^ ((row >> 2) & 1));
        const short* src = B + (size_t)(colBase + row) * K + (k0 + ls * 8);
        __builtin_amdgcn_global_load_lds(
            (__attribute__((address_space(1))) unsigned int*)src,
            (__attribute__((address_space(3))) unsigned int*)(sB + q * 8), 16, 0, 0);
      }
    }
    __syncthreads();
    bf16x8 av[FM], bv[FN];
#pragma unroll
    for (int i = 0; i < FM; i++) {
      int row = wm * FM * 16 + i * 16 + lr;
      av[i] = *(const bf16x8*)(sA + (row * 4 + (l4 ^ mrd)) * 8);
    }
#pragma unroll
    for (int j = 0; j < FN; j++) {
      int row = wn * FN * 16 + j * 16 + lr;
      bv[j] = *(const bf16x8*)(sB + (row * 4 + (l4 ^ mrd)) * 8);
    }
#pragma unroll
    for (int i = 0; i < FM; i++)
#pragma unroll
      for (int j = 0; j < FN; j++)
        acc[i][j] = __builtin_amdgcn_mfma_f32_16x16x32_bf16(av[i], bv[j], acc[i][j], 0, 0, 0);
  }
  // epilogue: C/D layout col=lane&15, row=4*(lane>>4)+reg (m89-verified)
#pragma unroll
  for (int i = 0; i < FM; i++) {
#pragma unroll
    for (int j = 0; j < FN; j++) {
      int r0 = rowBase + wm * FM * 16 + i * 16 + l4 * 4;
      int c = colBase + wn * FN * 16 + j * 16 + lr;
#pragma unroll
      for (int rr = 0; rr < 4; rr++) {
        size_t idx = (size_t)(r0 + rr) * N + c;
        float v = acc[i][j][rr];
        if (RESID) v += res[idx];
        C[idx] = v;
      }
    }
  }
}

// ---------------- depthwise causal conv1d (K=4) + bias + SiLU -> bf16 ----------------
__global__ __launch_bounds__(256) void conv_silu_k(const float* __restrict__ xz,
                                                   const float* __restrict__ cw,
                                                   const float* __restrict__ cb,
                                                   short* __restrict__ xiC) {
  int idx = blockIdx.x * 256 + threadIdx.x;  // over S*DI
  int s = idx / DIc, c = idx - s * DIc;
  float acc = cb[c];
  float w0 = cw[c * 4 + 0], w1 = cw[c * 4 + 1], w2 = cw[c * 4 + 2], w3 = cw[c * 4 + 3];
  float x0 = (s >= 3) ? xz[(size_t)(s - 3) * (2 * DIc) + c] : 0.f;
  float x1 = (s >= 2) ? xz[(size_t)(s - 2) * (2 * DIc) + c] : 0.f;
  float x2 = (s >= 1) ? xz[(size_t)(s - 1) * (2 * DIc) + c] : 0.f;
  float x3 = xz[(size_t)s * (2 * DIc) + c];
  acc += w0 * x0 + w1 * x1 + w2 * x2 + w3 * x3;
  float sv = acc / (1.f + __expf(-acc));
  xiC[idx] = f2bf(sv);
}

// ---------------- softplus(x + b) in place ----------------
__global__ __launch_bounds__(256) void softplus_k(float* __restrict__ dt,
                                                  const float* __restrict__ b) {
  int idx = blockIdx.x * 256 + threadIdx.x;
  int c = idx & (DIc - 1);
  float x = dt[idx] + b[c];
  dt[idx] = fmaxf(x, 0.f) + log1pf(__expf(-fabsf(x)));
}

// ---------------- A = -exp(A_log) ----------------
__global__ __launch_bounds__(256) void negA_k(const float* __restrict__ alog,
                                              float* __restrict__ Aval) {
  int i = blockIdx.x * 256 + threadIdx.x;
  Aval[i] = -__expf(alog[i]);
}

// ---------------- scan pass 1: per-chunk (prod a, local scan) ----------------
__global__ __launch_bounds__(256) void scan_pass1(const float* __restrict__ dt,
                                                  const short* __restrict__ u,
                                                  const float* __restrict__ bc,
                                                  const float* __restrict__ Aval,
                                                  float* __restrict__ Ap,
                                                  float* __restrict__ Hl) {
  const int j = blockIdx.x;
  const int d = blockIdx.y * 256 + threadIdx.x;
  __shared__ float sB[LCH][Nn];
  for (int q = threadIdx.x; q < LCH * Nn; q += 256) {
    int tt = q >> 4, n = q & 15;
    sB[tt][n] = bc[(size_t)(j * LCH + tt) * 32 + n];
  }
  __syncthreads();
  float Ar[Nn], h[Nn], ap[Nn];
#pragma unroll
  for (int n = 0; n < Nn; n++) { Ar[n] = Aval[d * Nn + n]; h[n] = 0.f; ap[n] = 1.f; }
  const int t0 = j * LCH;
  for (int tt = 0; tt < LCH; tt++) {
    size_t gi = (size_t)(t0 + tt) * DIc + d;
    float dtv = dt[gi];
    float uv = bf2f(u[gi]);
    float dtu = dtv * uv;
#pragma unroll
    for (int n = 0; n < Nn; n++) {
      float a = __expf(dtv * Ar[n]);
      h[n] = a * h[n] + dtu * sB[tt][n];
      ap[n] *= a;
    }
  }
  size_t base = ((size_t)j * DIc + d) * Nn;
#pragma unroll
  for (int n = 0; n < Nn; n++) { Ap[base + n] = ap[n]; Hl[base + n] = h[n]; }
}

// ---------------- scan combine: sequential over chunks ----------------
__global__ __launch_bounds__(256) void scan_combine(const float* __restrict__ Ap,
                                                    const float* __restrict__ Hl,
                                                    float* __restrict__ Hi) {
  int idx = blockIdx.x * 256 + threadIdx.x;  // over DI*N
  float h = 0.f;
  for (int j = 0; j < NCHc; j++) {
    size_t o = (size_t)j * DIc * Nn + idx;
    Hi[o] = h;
    h = Ap[o] * h + Hl[o];
  }
}

// ---------------- scan pass 2: emit y * silu(z) as bf16 ----------------
__global__ __launch_bounds__(256) void scan_pass2(const float* __restrict__ dt,
                                                  const short* __restrict__ u,
                                                  const float* __restrict__ bc,
                                                  const float* __restrict__ Aval,
                                                  const float* __restrict__ Hinit,
                                                  const float* __restrict__ Dp,
                                                  const float* __restrict__ xz,
                                                  short* __restrict__ y) {
  const int j = blockIdx.x;
  const int d = blockIdx.y * 256 + threadIdx.x;
  __shared__ float sB[LCH][Nn], sC[LCH][Nn];
  for (int q = threadIdx.x; q < LCH * Nn; q += 256) {
    int tt = q >> 4, n = q & 15;
    size_t r = (size_t)(j * LCH + tt) * 32;
    sB[tt][n] = bc[r + n];
    sC[tt][n] = bc[r + 16 + n];
  }
  __syncthreads();
  float Ar[Nn], h[Nn];
  size_t hb = ((size_t)j * DIc + d) * Nn;
#pragma unroll
  for (int n = 0; n < Nn; n++) { Ar[n] = Aval[d * Nn + n]; h[n] = Hinit[hb + n]; }
  float dp = Dp[d];
  const int t0 = j * LCH;
  for (int tt = 0; tt < LCH; tt++) {
    size_t gi = (size_t)(t0 + tt) * DIc + d;
    float dtv = dt[gi];
    float uv = bf2f(u[gi]);
    float dtu = dtv * uv;
    float yv = dp * uv;
#pragma unroll
    for (int n = 0; n < Nn; n++) {
      float a = __expf(dtv * Ar[n]);
      h[n] = a * h[n] + dtu * sB[tt][n];
      yv += h[n] * sC[tt][n];
    }
    float zv = xz[(size_t)(t0 + tt) * (2 * DIc) + DIc + d];
    float sz = zv / (1.f + __expf(-zv));
    y[gi] = f2bf(yv * sz);
  }
}

// ---------------- host orchestration ----------------
extern "C" void kernel_launch(void* const* d_in, const int* in_sizes, int n_in,
                              void* d_out, int out_size, void* d_ws, size_t ws_size,
                              hipStream_t stream) {
  (void)in_sizes; (void)n_in; (void)out_size; (void)ws_size;
  const int* ids = (const int*)d_in[0];
  const float* emb = (const float*)d_in[1];
  const float* in_proj_w = (const float*)d_in[2];
  const float* conv_w = (const float*)d_in[3];
  const float* conv_b = (const float*)d_in[4];
  const float* x_proj_w = (const float*)d_in[5];
  const float* dt_proj_w = (const float*)d_in[6];
  const float* dt_proj_b = (const float*)d_in[7];
  const float* A_log = (const float*)d_in[8];
  const float* D_param = (const float*)d_in[9];
  const float* out_proj_w = (const float*)d_in[10];
  const float* norm_w = (const float*)d_in[11];
  const float* norm_f_w = (const float*)d_in[12];
  const float* lm_head_w = (const float*)d_in[13];
  float* logits = (float*)d_out;

  // ---- allocation: only lm_head-phase-live buffers in d_ws; the rest of the
  // scratch lives inside d_out (262MB) and is dead before the final GEMM,
  // which fully overwrites d_out. ----
  char* ws = (char*)d_ws;
  size_t woff = 0;
  auto walloc = [&](size_t bytes) { void* p = ws + woff; woff += (bytes + 255) & ~(size_t)255; return p; };
  float* x     = (float*)walloc((size_t)Ss * Dd * 4);          // residual stream
  short* xfbf  = (short*)walloc((size_t)Ss * Dd * 2);          // final norm out
  short* w_lm  = (short*)walloc((size_t)Vv * Dd * 2);          // lm_head bf16
  float* Aval  = (float*)walloc((size_t)DIc * Nn * 4);

  char* sc = (char*)d_out;
  size_t soff = 0;
  auto salloc = [&](size_t bytes) { void* p = sc + soff; soff += (bytes + 255) & ~(size_t)255; return p; };
  float* xz   = (float*)salloc((size_t)Ss * 2 * DIc * 4);      // 33.6MB
  float* dtb  = (float*)salloc((size_t)Ss * DIc * 4);          // 16.8MB
  float* bc   = (float*)salloc((size_t)Ss * 32 * 4);
  float* Ap   = (float*)salloc((size_t)NCHc * DIc * Nn * 4);
  float* Hl   = (float*)salloc((size_t)NCHc * DIc * Nn * 4);
  float* Hi   = (float*)salloc((size_t)NCHc * DIc * Nn * 4);
  short* hbf  = (short*)salloc((size_t)Ss * Dd * 2);
  short* xiC  = (short*)salloc((size_t)Ss * DIc * 2);
  short* ybf  = (short*)salloc((size_t)Ss * DIc * 2);
  short* w_in = (short*)salloc((size_t)NLay * 2 * DIc * Dd * 2);
  short* w_xp = (short*)salloc((size_t)NLay * 2 * Nn * DIc * 2);
  short* w_dt = (short*)salloc((size_t)NLay * DIc * DIc * 2);
  short* w_out= (short*)salloc((size_t)NLay * Dd * DIc * 2);

  auto cvt = [&](const float* src, short* dst, size_t n) {
    int n4 = (int)(n / 4);
    cvt_k<<<dim3((n4 + 255) / 256), dim3(256), 0, stream>>>(src, dst, n4);
  };
  cvt(in_proj_w, w_in, (size_t)NLay * 2 * DIc * Dd);
  cvt(x_proj_w,  w_xp, (size_t)NLay * 2 * Nn * DIc);
  cvt(dt_proj_w, w_dt, (size_t)NLay * DIc * DIc);
  cvt(out_proj_w,w_out,(size_t)NLay * Dd * DIc);
  cvt(lm_head_w, w_lm, (size_t)Vv * Dd);

  embed_k<<<dim3(Ss), dim3(256), 0, stream>>>(ids, emb, x);

  for (int l = 0; l < NLay; l++) {
    rmsnorm_k<<<dim3(Ss), dim3(256), 0, stream>>>(x, norm_w + (size_t)l * Dd, hbf);
    // in_proj: (2048 x 4096) = h (2048x1024) * W^T
    gemm_bt<128, 128, 2, 2, false><<<dim3(2 * DIc / 128, Ss / 128), dim3(256), 0, stream>>>(
        hbf, w_in + (size_t)l * 2 * DIc * Dd, xz, nullptr, Ss, 2 * DIc, Dd);
    conv_silu_k<<<dim3(Ss * DIc / 256), dim3(256), 0, stream>>>(
        xz, conv_w + (size_t)l * DIc * Kc, conv_b + (size_t)l * DIc, xiC);
    // x_proj: (2048 x 32)
    gemm_bt<128, 32, 4, 1, false><<<dim3(1, Ss / 128), dim3(256), 0, stream>>>(
        xiC, w_xp + (size_t)l * 2 * Nn * DIc, bc, nullptr, Ss, 32, DIc);
    // dt_proj: (2048 x 2048)
    gemm_bt<128, 128, 2, 2, false><<<dim3(DIc / 128, Ss / 128), dim3(256), 0, stream>>>(
        xiC, w_dt + (size_t)l * DIc * DIc, dtb, nullptr, Ss, DIc, DIc);
    softplus_k<<<dim3(Ss * DIc / 256), dim3(256), 0, stream>>>(dtb, dt_proj_b + (size_t)l * DIc);
    negA_k<<<dim3(DIc * Nn / 256), dim3(256), 0, stream>>>(A_log + (size_t)l * DIc * Nn, Aval);
    scan_pass1<<<dim3(NCHc, DIc / 256), dim3(256), 0, stream>>>(dtb, xiC, bc, Aval, Ap, Hl);
    scan_combine<<<dim3(DIc * Nn / 256), dim3(256), 0, stream>>>(Ap, Hl, Hi);
    scan_pass2<<<dim3(NCHc, DIc / 256), dim3(256), 0, stream>>>(dtb, xiC, bc, Aval, Hi,
        D_param + (size_t)l * DIc, xz, ybf);
    // out_proj with fused residual: x = x + y @ W^T  (1024 cols)
    gemm_bt<128, 128, 2, 2, true><<<dim3(Dd / 128, Ss / 128), dim3(256), 0, stream>>>(
        ybf, w_out + (size_t)l * Dd * DIc, x, x, Ss, Dd, DIc);
  }

  rmsnorm_k<<<dim3(Ss), dim3(256), 0, stream>>>(x, norm_f_w, xfbf);
  // lm_head: (2048 x 32000) — fully overwrites d_out (including scratch regions)
  gemm_bt<128, 128, 2, 2, false><<<dim3(Vv / 128, Ss / 128), dim3(256), 0, stream>>>(
      xfbf, w_lm, logits, nullptr, Ss, Vv, Dd);
}

// Round 2
// 856.334 us; speedup vs baseline: 1.0677x; 1.0677x over previous
//
#include <hip/hip_runtime.h>
#include <hip/hip_bf16.h>
#include <stdint.h>
#include <stddef.h>

// ---- model dims ----
#define Vv   32000
#define Dd   1024
#define NLay 2
#define Ss   2048
#define Nn   16
#define Kc   4
#define DIc  2048
#define EPSf 1e-5f
#define LCH  64
#define NCHc (Ss / LCH)   // 32 chunks
#define CATR 2176         // dt_proj (2048) + x_proj (32) rows, padded to 17*128

typedef __attribute__((ext_vector_type(8))) short bf16x8;
typedef __attribute__((ext_vector_type(4))) float f32x4;

__device__ __forceinline__ short f2bf(float f) {
  union { float f; unsigned u; } a; a.f = f;
  return (short)((a.u + 0x7FFFu + ((a.u >> 16) & 1u)) >> 16);  // RNE
}
__device__ __forceinline__ float bf2f(short s) {
  union { unsigned u; float f; } a; a.u = ((unsigned)(unsigned short)s) << 16;
  return a.f;
}

// ---------------- f32 -> bf16 convert (vectorized) ----------------
__global__ __launch_bounds__(256) void cvt_k(const float* __restrict__ in,
                                             short* __restrict__ out, int n4) {
  int i = blockIdx.x * 256 + threadIdx.x;
  if (i < n4) {
    float4 v = ((const float4*)in)[i];
    short4 o;
    o.x = f2bf(v.x); o.y = f2bf(v.y); o.z = f2bf(v.z); o.w = f2bf(v.w);
    ((short4*)out)[i] = o;
  }
}

// ---------------- embedding gather ----------------
__global__ __launch_bounds__(256) void embed_k(const int* __restrict__ ids,
                                               const float* __restrict__ emb,
                                               float* __restrict__ x) {
  int s = blockIdx.x;
  int id = ids[s];
  const float4* src = (const float4*)(emb + (size_t)id * Dd);
  float4* dst = (float4*)(x + (size_t)s * Dd);
  dst[threadIdx.x] = src[threadIdx.x];   // 256 threads * 4 = 1024
}

// ---------------- RMSNorm -> bf16 ----------------
__global__ __launch_bounds__(256) void rmsnorm_k(const float* __restrict__ x,
                                                 const float* __restrict__ w,
                                                 short* __restrict__ o) {
  int s = blockIdx.x, t = threadIdx.x;
  float4 v = ((const float4*)(x + (size_t)s * Dd))[t];
  float ss = v.x * v.x + v.y * v.y + v.z * v.z + v.w * v.w;
#pragma unroll
  for (int off = 32; off; off >>= 1) ss += __shfl_down(ss, off);
  __shared__ float red[4];
  if ((t & 63) == 0) red[t >> 6] = ss;
  __syncthreads();
  ss = red[0] + red[1] + red[2] + red[3];
  float rinv = rsqrtf(ss * (1.0f / Dd) + EPSf);
  float4 wv = ((const float4*)w)[t];
  short4 ov;
  ov.x = f2bf(v.x * rinv * wv.x);
  ov.y = f2bf(v.y * rinv * wv.y);
  ov.z = f2bf(v.z * rinv * wv.z);
  ov.w = f2bf(v.w * rinv * wv.w);
  ((short4*)(o + (size_t)s * Dd))[t] = ov;
}

// ---------------- bf16 B^T GEMM: C[M,N] = A[M,K] * B[N,K]^T ----------------
// m97-structure (128^2, BK=32, global_load_lds 16B, XOR slot swizzle) plus:
//  * 1D grid, M-fast tile order inside bijective XCD chunks (T1): the 16
//    M-tiles sharing a B-panel run consecutively on one XCD -> B fetched ~once.
//  * RESID: C = A*B^T + res (residual stream update)
//  * CAT:   B is [dt_proj ; x_proj] rows; cols <2048 -> softplus(v + bias[c])
//           into C (stride 2048); cols 2048..2079 -> raw into C2 (stride 32).
template <int BM, int BN, int WM, int WN, bool RESID, bool CAT>
__global__ __launch_bounds__(256) void gemm_bt(const short* __restrict__ A,
                                               const short* __restrict__ B,
                                               float* C, const float* __restrict__ resb,
                                               float* C2, int M, int N, int K, int nMt) {
  constexpr int BK = 32;
  constexpr int FM = BM / (WM * 16);
  constexpr int FN = BN / (WN * 16);
  constexpr int A_SLOTS = BM * (BK / 8);  // 16B slots
  constexpr int B_SLOTS = BN * (BK / 8);
  __shared__ short sA[BM * BK];
  __shared__ short sB[BN * BK];
  const int t = threadIdx.x;
  const int lane = t & 63;
  const int w = t >> 6;
  const int wm = w / WN, wn = w % WN;
  // XCD-chunked, M-fast tile mapping (nwg % 8 == 0 for all our launches)
  const int nwg = gridDim.x;
  const int chunk = nwg >> 3;
  const int wg = (blockIdx.x & 7) * chunk + (blockIdx.x >> 3);
  const int mi = wg % nMt;
  const int ni = wg / nMt;
  const int rowBase = mi * BM;
  const int colBase = ni * BN;
  const int l4 = lane >> 4;
  const int lr = lane & 15;
  const int mrd = ((lr & 3) ^ ((lr >> 2) & 1));  // swizzle mask for frag rows

  f32x4 acc[FM][FN];
#pragma unroll
  for (int i = 0; i < FM; i++)
#pragma unroll
    for (int j = 0; j < FN; j++) acc[i][j] = f32x4{0.f, 0.f, 0.f, 0.f};

  for (int k0 = 0; k0 < K; k0 += BK) {
    __syncthreads();
#pragma unroll
    for (int i = 0; i < (A_SLOTS + 255) / 256; i++) {
      int q = i * 256 + t;
      if (A_SLOTS % 256 == 0 || q < A_SLOTS) {
        int row = q >> 2, ps = q & 3;
        int ls = ps ^ ((row & 3) ^ ((row >> 2) & 1));
        const short* src = A + (size_t)(rowBase + row) * K + (k0 + ls * 8);
        __builtin_amdgcn_global_load_lds(
            (__attribute__((address_space(1))) unsigned int*)src,
            (__attribute__((address_space(3))) unsigned int*)(sA + q * 8), 16, 0, 0);
      }
    }
#pragma unroll
    for (int i = 0; i < (B_SLOTS + 255) / 256; i++) {
      int q = i * 256 + t;
      if (B_SLOTS % 256 == 0 || q < B_SLOTS) {
        int row = q >> 2, ps = q & 3;
        int ls = ps ^ ((row & 3) ^ ((row >> 2) & 1));
        const short* src = B + (size_t)(colBase + row) * K + (k0 + ls * 8);
        __builtin_amdgcn_global_load_lds(
            (__attribute__((address_space(1))) unsigned int*)src,
            (__attribute__((address_space(3))) unsigned int*)(sB + q * 8), 16, 0, 0);
      }
    }
    __syncthreads();
    bf16x8 av[FM], bv[FN];
#pragma unroll
    for (int i = 0; i < FM; i++) {
      int row = wm * FM * 16 + i * 16 + lr;
      av[i] = *(const bf16x8*)(sA + (row * 4 + (l4 ^ mrd)) * 8);
    }
#pragma unroll
    for (int j = 0; j < FN; j++) {
      int row = wn * FN * 16 + j * 16 + lr;
      bv[j] = *(const bf16x8*)(sB + (row * 4 + (l4 ^ mrd)) * 8);
    }
#pragma unroll
    for (int i = 0; i < FM; i++)
#pragma unroll
      for (int j = 0; j < FN; j++)
        acc[i][j] = __builtin_amdgcn_mfma_f32_16x16x32_bf16(av[i], bv[j], acc[i][j], 0, 0, 0);
  }
  // epilogue: C/D layout col=lane&15, row=4*(lane>>4)+reg (m89-verified)
#pragma unroll
  for (int i = 0; i < FM; i++) {
#pragma unroll
    for (int j = 0; j < FN; j++) {
      int r0 = rowBase + wm * FM * 16 + i * 16 + l4 * 4;
      int c = colBase + wn * FN * 16 + j * 16 + lr;
#pragma unroll
      for (int rr = 0; rr < 4; rr++) {
        int r = r0 + rr;
        float v = acc[i][j][rr];
        if (CAT) {
          if (c < DIc) {
            float xv = v + resb[c];  // dt bias + softplus fused
            C[(size_t)r * DIc + c] = fmaxf(xv, 0.f) + log1pf(__expf(-fabsf(xv)));
          } else if (c < DIc + 2 * Nn) {
            C2[(size_t)r * (2 * Nn) + (c - DIc)] = v;
          }
        } else {
          size_t idx = (size_t)r * N + c;
          if (RESID) v += resb[idx];
          C[idx] = v;
        }
      }
    }
  }
}

// ---------------- depthwise causal conv1d (K=4) + bias + SiLU -> bf16 ----------------
__global__ __launch_bounds__(256) void conv_silu_k(const float* __restrict__ xz,
                                                   const float* __restrict__ cw,
                                                   const float* __restrict__ cb,
                                                   short* __restrict__ xiC) {
  int idx = blockIdx.x * 256 + threadIdx.x;  // over S*DI
  int s = idx / DIc, c = idx - s * DIc;
  float acc = cb[c];
  float w0 = cw[c * 4 + 0], w1 = cw[c * 4 + 1], w2 = cw[c * 4 + 2], w3 = cw[c * 4 + 3];
  float x0 = (s >= 3) ? xz[(size_t)(s - 3) * (2 * DIc) + c] : 0.f;
  float x1 = (s >= 2) ? xz[(size_t)(s - 2) * (2 * DIc) + c] : 0.f;
  float x2 = (s >= 1) ? xz[(size_t)(s - 1) * (2 * DIc) + c] : 0.f;
  float x3 = xz[(size_t)s * (2 * DIc) + c];
  acc += w0 * x0 + w1 * x1 + w2 * x2 + w3 * x3;
  float sv = acc / (1.f + __expf(-acc));
  xiC[idx] = f2bf(sv);
}

// ---------------- A = -exp(A_log) (both layers) ----------------
__global__ __launch_bounds__(256) void negA_k(const float* __restrict__ alog,
                                              float* __restrict__ Aval) {
  int i = blockIdx.x * 256 + threadIdx.x;
  Aval[i] = -__expf(alog[i]);
}

// ---------------- scan pass 1: per-chunk (prod a, local scan) ----------------
__global__ __launch_bounds__(256) void scan_pass1(const float* __restrict__ dt,
                                                  const short* __restrict__ u,
                                                  const float* __restrict__ bc,
                                                  const float* __restrict__ Aval,
                                                  float* __restrict__ Ap,
                                                  float* __restrict__ Hl) {
  const int j = blockIdx.x;
  const int d = blockIdx.y * 256 + threadIdx.x;
  __shared__ float sB[LCH][Nn];
  for (int q = threadIdx.x; q < LCH * Nn; q += 256) {
    int tt = q >> 4, n = q & 15;
    sB[tt][n] = bc[(size_t)(j * LCH + tt) * 32 + n];
  }
  __syncthreads();
  float Ar[Nn], h[Nn], ap[Nn];
#pragma unroll
  for (int n = 0; n < Nn; n++) { Ar[n] = Aval[d * Nn + n]; h[n] = 0.f; ap[n] = 1.f; }
  const int t0 = j * LCH;
  for (int tt = 0; tt < LCH; tt++) {
    size_t gi = (size_t)(t0 + tt) * DIc + d;
    float dtv = dt[gi];
    float uv = bf2f(u[gi]);
    float dtu = dtv * uv;
#pragma unroll
    for (int n = 0; n < Nn; n++) {
      float a = __expf(dtv * Ar[n]);
      h[n] = a * h[n] + dtu * sB[tt][n];
      ap[n] *= a;
    }
  }
  size_t base = ((size_t)j * DIc + d) * Nn;
#pragma unroll
  for (int n = 0; n < Nn; n++) { Ap[base + n] = ap[n]; Hl[base + n] = h[n]; }
}

// ---------------- scan combine: sequential over chunks ----------------
__global__ __launch_bounds__(256) void scan_combine(const float* __restrict__ Ap,
                                                    const float* __restrict__ Hl,
                                                    float* __restrict__ Hi) {
  int idx = blockIdx.x * 256 + threadIdx.x;  // over DI*N
  float h = 0.f;
  for (int j = 0; j < NCHc; j++) {
    size_t o = (size_t)j * DIc * Nn + idx;
    Hi[o] = h;
    h = Ap[o] * h + Hl[o];
  }
}

// ---------------- scan pass 2: emit y * silu(z) as bf16 ----------------
__global__ __launch_bounds__(256) void scan_pass2(const float* __restrict__ dt,
                                                  const short* __restrict__ u,
                                                  const float* __restrict__ bc,
                                                  const float* __restrict__ Aval,
                                                  const float* __restrict__ Hinit,
                                                  const float* __restrict__ Dp,
                                                  const float* __restrict__ xz,
                                                  short* __restrict__ y) {
  const int j = blockIdx.x;
  const int d = blockIdx.y * 256 + threadIdx.x;
  __shared__ float sB[LCH][Nn], sC[LCH][Nn];
  for (int q = threadIdx.x; q < LCH * Nn; q += 256) {
    int tt = q >> 4, n = q & 15;
    size_t r = (size_t)(j * LCH + tt) * 32;
    sB[tt][n] = bc[r + n];
    sC[tt][n] = bc[r + 16 + n];
  }
  __syncthreads();
  float Ar[Nn], h[Nn];
  size_t hb = ((size_t)j * DIc + d) * Nn;
#pragma unroll
  for (int n = 0; n < Nn; n++) { Ar[n] = Aval[d * Nn + n]; h[n] = Hinit[hb + n]; }
  float dp = Dp[d];
  const int t0 = j * LCH;
  for (int tt = 0; tt < LCH; tt++) {
    size_t gi = (size_t)(t0 + tt) * DIc + d;
    float dtv = dt[gi];
    float uv = bf2f(u[gi]);
    float dtu = dtv * uv;
    float yv = dp * uv;
#pragma unroll
    for (int n = 0; n < Nn; n++) {
      float a = __expf(dtv * Ar[n]);
      h[n] = a * h[n] + dtu * sB[tt][n];
      yv += h[n] * sC[tt][n];
    }
    float zv = xz[(size_t)(t0 + tt) * (2 * DIc) + DIc + d];
    float sz = zv / (1.f + __expf(-zv));
    y[gi] = f2bf(yv * sz);
  }
}

// ---------------- host orchestration ----------------
extern "C" void kernel_launch(void* const* d_in, const int* in_sizes, int n_in,
                              void* d_out, int out_size, void* d_ws, size_t ws_size,
                              hipStream_t stream) {
  (void)in_sizes; (void)n_in; (void)out_size; (void)ws_size;
  const int* ids = (const int*)d_in[0];
  const float* emb = (const float*)d_in[1];
  const float* in_proj_w = (const float*)d_in[2];
  const float* conv_w = (const float*)d_in[3];
  const float* conv_b = (const float*)d_in[4];
  const float* x_proj_w = (const float*)d_in[5];
  const float* dt_proj_w = (const float*)d_in[6];
  const float* dt_proj_b = (const float*)d_in[7];
  const float* A_log = (const float*)d_in[8];
  const float* D_param = (const float*)d_in[9];
  const float* out_proj_w = (const float*)d_in[10];
  const float* norm_w = (const float*)d_in[11];
  const float* norm_f_w = (const float*)d_in[12];
  const float* lm_head_w = (const float*)d_in[13];
  float* logits = (float*)d_out;

  // ---- allocation: only lm_head-phase-live buffers in d_ws; the rest of the
  // scratch lives inside d_out (262MB) and is dead before the final GEMM,
  // which fully overwrites d_out. ----
  char* ws = (char*)d_ws;
  size_t woff = 0;
  auto walloc = [&](size_t bytes) { void* p = ws + woff; woff += (bytes + 255) & ~(size_t)255; return p; };
  float* x     = (float*)walloc((size_t)Ss * Dd * 4);          // residual stream
  short* xfbf  = (short*)walloc((size_t)Ss * Dd * 2);          // final norm out
  short* w_lm  = (short*)walloc((size_t)Vv * Dd * 2);          // lm_head bf16
  float* Aval  = (float*)walloc((size_t)NLay * DIc * Nn * 4);

  char* sc = (char*)d_out;
  size_t soff = 0;
  auto salloc = [&](size_t bytes) { void* p = sc + soff; soff += (bytes + 255) & ~(size_t)255; return p; };
  float* xz   = (float*)salloc((size_t)Ss * 2 * DIc * 4);      // 33.6MB
  float* dtb  = (float*)salloc((size_t)Ss * DIc * 4);          // 16.8MB
  float* bc   = (float*)salloc((size_t)Ss * 32 * 4);
  float* Ap   = (float*)salloc((size_t)NCHc * DIc * Nn * 4);
  float* Hl   = (float*)salloc((size_t)NCHc * DIc * Nn * 4);
  float* Hi   = (float*)salloc((size_t)NCHc * DIc * Nn * 4);
  short* hbf  = (short*)salloc((size_t)Ss * Dd * 2);
  short* xiC  = (short*)salloc((size_t)Ss * DIc * 2);
  short* ybf  = (short*)salloc((size_t)Ss * DIc * 2);
  short* w_in = (short*)salloc((size_t)NLay * 2 * DIc * Dd * 2);
  short* w_cat= (short*)salloc((size_t)NLay * CATR * DIc * 2); // [dt;xp] rows
  short* w_out= (short*)salloc((size_t)NLay * Dd * DIc * 2);

  auto cvt = [&](const float* src, short* dst, size_t n) {
    int n4 = (int)(n / 4);
    cvt_k<<<dim3((n4 + 255) / 256), dim3(256), 0, stream>>>(src, dst, n4);
  };
  cvt(in_proj_w, w_in, (size_t)NLay * 2 * DIc * Dd);
  cvt(out_proj_w,w_out,(size_t)NLay * Dd * DIc);
  cvt(lm_head_w, w_lm, (size_t)Vv * Dd);
  for (int l = 0; l < NLay; l++) {
    // dt_proj rows 0..2047, x_proj rows 2048..2079 of the cat weight
    cvt(dt_proj_w + (size_t)l * DIc * DIc, w_cat + (size_t)l * CATR * DIc, (size_t)DIc * DIc);
    cvt(x_proj_w + (size_t)l * 2 * Nn * DIc,
        w_cat + (size_t)l * CATR * DIc + (size_t)DIc * DIc, (size_t)2 * Nn * DIc);
  }
  negA_k<<<dim3(NLay * DIc * Nn / 256), dim3(256), 0, stream>>>(A_log, Aval);

  embed_k<<<dim3(Ss), dim3(256), 0, stream>>>(ids, emb, x);

  for (int l = 0; l < NLay; l++) {
    rmsnorm_k<<<dim3(Ss), dim3(256), 0, stream>>>(x, norm_w + (size_t)l * Dd, hbf);
    // in_proj: (2048 x 4096), grid 16*32=512
    gemm_bt<128, 128, 2, 2, false, false><<<dim3(16 * 32), dim3(256), 0, stream>>>(
        hbf, w_in + (size_t)l * 2 * DIc * Dd, xz, nullptr, nullptr, Ss, 2 * DIc, Dd, 16);
    conv_silu_k<<<dim3(Ss * DIc / 256), dim3(256), 0, stream>>>(
        xz, conv_w + (size_t)l * DIc * Kc, conv_b + (size_t)l * DIc, xiC);
    // cat GEMM: dt_proj (softplus fused) + x_proj, grid 16*17=272
    gemm_bt<128, 128, 2, 2, false, true><<<dim3(16 * 17), dim3(256), 0, stream>>>(
        xiC, w_cat + (size_t)l * CATR * DIc, dtb, dt_proj_b + (size_t)l * DIc, bc,
        Ss, CATR, DIc, 16);
    scan_pass1<<<dim3(NCHc, DIc / 256), dim3(256), 0, stream>>>(
        dtb, xiC, bc, Aval + (size_t)l * DIc * Nn, Ap, Hl);
    scan_combine<<<dim3(DIc * Nn / 256), dim3(256), 0, stream>>>(Ap, Hl, Hi);
    scan_pass2<<<dim3(NCHc, DIc / 256), dim3(256), 0, stream>>>(
        dtb, xiC, bc, Aval + (size_t)l * DIc * Nn, Hi,
        D_param + (size_t)l * DIc, xz, ybf);
    // out_proj with fused residual: x = x + y @ W^T, grid 16*8=128
    gemm_bt<128, 128, 2, 2, true, false><<<dim3(16 * 8), dim3(256), 0, stream>>>(
        ybf, w_out + (size_t)l * Dd * DIc, x, x, nullptr, Ss, Dd, DIc, 16);
  }

  rmsnorm_k<<<dim3(Ss), dim3(256), 0, stream>>>(x, norm_f_w, xfbf);
  // lm_head: (2048 x 32000), grid 16*250=4000 — fully overwrites d_out
  gemm_bt<128, 128, 2, 2, false, false><<<dim3(16 * 250), dim3(256), 0, stream>>>(
      xfbf, w_lm, logits, nullptr, nullptr, Ss, Vv, Dd, 16);
}

// Round 3
// 735.346 us; speedup vs baseline: 1.2434x; 1.1645x over previous
//
#include <hip/hip_runtime.h>
#include <hip/hip_bf16.h>
#include <stdint.h>
#include <stddef.h>

// ---- model dims ----
#define Vv   32000
#define Dd   1024
#define NLay 2
#define Ss   2048
#define Nn   16
#define Kc   4
#define DIc  2048
#define EPSf 1e-5f
#define LCH  32
#define NCHc (Ss / LCH)   // 64 chunks
#define CATR 2176         // dt_proj (2048) + x_proj (32) rows, padded to 17*128

typedef __attribute__((ext_vector_type(8))) short bf16x8;
typedef __attribute__((ext_vector_type(4))) float f32x4;

__device__ __forceinline__ short f2bf(float f) {
  union { float f; unsigned u; } a; a.f = f;
  return (short)((a.u + 0x7FFFu + ((a.u >> 16) & 1u)) >> 16);  // RNE
}
__device__ __forceinline__ float bf2f(short s) {
  union { unsigned u; float f; } a; a.u = ((unsigned)(unsigned short)s) << 16;
  return a.f;
}

// ---------------- batched f32 -> bf16 convert (1 launch for all weights) ----------------
struct CvtSeg { const float* s; short* d; unsigned n4; };
struct CvtBatch { CvtSeg seg[7]; unsigned tot4; };
__global__ __launch_bounds__(256) void cvt_all_k(CvtBatch b) {
  for (unsigned idx = blockIdx.x * 256 + threadIdx.x; idx < b.tot4;
       idx += gridDim.x * 256) {
    unsigned r = idx;
    int sg = 0;
    while (sg < 6 && r >= b.seg[sg].n4) { r -= b.seg[sg].n4; ++sg; }
    float4 v = ((const float4*)b.seg[sg].s)[r];
    short4 o;
    o.x = f2bf(v.x); o.y = f2bf(v.y); o.z = f2bf(v.z); o.w = f2bf(v.w);
    ((short4*)b.seg[sg].d)[r] = o;
  }
}

// ---------------- embedding gather ----------------
__global__ __launch_bounds__(256) void embed_k(const int* __restrict__ ids,
                                               const float* __restrict__ emb,
                                               float* __restrict__ x) {
  int s = blockIdx.x;
  int id = ids[s];
  const float4* src = (const float4*)(emb + (size_t)id * Dd);
  float4* dst = (float4*)(x + (size_t)s * Dd);
  dst[threadIdx.x] = src[threadIdx.x];   // 256 threads * 4 = 1024
}

// ---------------- RMSNorm -> bf16 ----------------
__global__ __launch_bounds__(256) void rmsnorm_k(const float* __restrict__ x,
                                                 const float* __restrict__ w,
                                                 short* __restrict__ o) {
  int s = blockIdx.x, t = threadIdx.x;
  float4 v = ((const float4*)(x + (size_t)s * Dd))[t];
  float ss = v.x * v.x + v.y * v.y + v.z * v.z + v.w * v.w;
#pragma unroll
  for (int off = 32; off; off >>= 1) ss += __shfl_down(ss, off);
  __shared__ float red[4];
  if ((t & 63) == 0) red[t >> 6] = ss;
  __syncthreads();
  ss = red[0] + red[1] + red[2] + red[3];
  float rinv = rsqrtf(ss * (1.0f / Dd) + EPSf);
  float4 wv = ((const float4*)w)[t];
  short4 ov;
  ov.x = f2bf(v.x * rinv * wv.x);
  ov.y = f2bf(v.y * rinv * wv.y);
  ov.z = f2bf(v.z * rinv * wv.z);
  ov.w = f2bf(v.w * rinv * wv.w);
  ((short4*)(o + (size_t)s * Dd))[t] = ov;
}

// ---------------- 128^2 bf16 B^T GEMM (m97 structure) for layer GEMMs ----------------
template <int BM, int BN, int WM, int WN, bool RESID, bool CAT>
__global__ __launch_bounds__(256) void gemm_bt(const short* __restrict__ A,
                                               const short* __restrict__ B,
                                               float* C, const float* __restrict__ resb,
                                               float* C2, int M, int N, int K, int nMt) {
  constexpr int BK = 32;
  constexpr int FM = BM / (WM * 16);
  constexpr int FN = BN / (WN * 16);
  constexpr int A_SLOTS = BM * (BK / 8);  // 16B slots
  constexpr int B_SLOTS = BN * (BK / 8);
  __shared__ short sA[BM * BK];
  __shared__ short sB[BN * BK];
  const int t = threadIdx.x;
  const int lane = t & 63;
  const int w = t >> 6;
  const int wm = w / WN, wn = w % WN;
  const int nwg = gridDim.x;
  const int chunk = nwg >> 3;
  const int wg = (blockIdx.x & 7) * chunk + (blockIdx.x >> 3);
  const int mi = wg % nMt;
  const int ni = wg / nMt;
  const int rowBase = mi * BM;
  const int colBase = ni * BN;
  const int l4 = lane >> 4;
  const int lr = lane & 15;
  const int mrd = ((lr & 3) ^ ((lr >> 2) & 1));

  f32x4 acc[FM][FN];
#pragma unroll
  for (int i = 0; i < FM; i++)
#pragma unroll
    for (int j = 0; j < FN; j++) acc[i][j] = f32x4{0.f, 0.f, 0.f, 0.f};

  for (int k0 = 0; k0 < K; k0 += BK) {
    __syncthreads();
#pragma unroll
    for (int i = 0; i < (A_SLOTS + 255) / 256; i++) {
      int q = i * 256 + t;
      if (A_SLOTS % 256 == 0 || q < A_SLOTS) {
        int row = q >> 2, ps = q & 3;
        int ls = ps ^ ((row & 3) ^ ((row >> 2) & 1));
        const short* src = A + (size_t)(rowBase + row) * K + (k0 + ls * 8);
        __builtin_amdgcn_global_load_lds(
            (__attribute__((address_space(1))) unsigned int*)src,
            (__attribute__((address_space(3))) unsigned int*)(sA + q * 8), 16, 0, 0);
      }
    }
#pragma unroll
    for (int i = 0; i < (B_SLOTS + 255) / 256; i++) {
      int q = i * 256 + t;
      if (B_SLOTS % 256 == 0 || q < B_SLOTS) {
        int row = q >> 2, ps = q & 3;
        int ls = ps ^ ((row & 3) ^ ((row >> 2) & 1));
        const short* src = B + (size_t)(colBase + row) * K + (k0 + ls * 8);
        __builtin_amdgcn_global_load_lds(
            (__attribute__((address_space(1))) unsigned int*)src,
            (__attribute__((address_space(3))) unsigned int*)(sB + q * 8), 16, 0, 0);
      }
    }
    __syncthreads();
    bf16x8 av[FM], bv[FN];
#pragma unroll
    for (int i = 0; i < FM; i++) {
      int row = wm * FM * 16 + i * 16 + lr;
      av[i] = *(const bf16x8*)(sA + (row * 4 + (l4 ^ mrd)) * 8);
    }
#pragma unroll
    for (int j = 0; j < FN; j++) {
      int row = wn * FN * 16 + j * 16 + lr;
      bv[j] = *(const bf16x8*)(sB + (row * 4 + (l4 ^ mrd)) * 8);
    }
#pragma unroll
    for (int i = 0; i < FM; i++)
#pragma unroll
      for (int j = 0; j < FN; j++)
        acc[i][j] = __builtin_amdgcn_mfma_f32_16x16x32_bf16(av[i], bv[j], acc[i][j], 0, 0, 0);
  }
#pragma unroll
  for (int i = 0; i < FM; i++) {
#pragma unroll
    for (int j = 0; j < FN; j++) {
      int r0 = rowBase + wm * FM * 16 + i * 16 + l4 * 4;
      int c = colBase + wn * FN * 16 + j * 16 + lr;
#pragma unroll
      for (int rr = 0; rr < 4; rr++) {
        int r = r0 + rr;
        float v = acc[i][j][rr];
        if (CAT) {
          if (c < DIc) {
            float xv = v + resb[c];  // dt bias + softplus fused
            C[(size_t)r * DIc + c] = fmaxf(xv, 0.f) + log1pf(__expf(-fabsf(xv)));
          } else if (c < DIc + 2 * Nn) {
            C2[(size_t)r * (2 * Nn) + (c - DIc)] = v;
          }
        } else {
          size_t idx = (size_t)r * N + c;
          if (RESID) v += resb[idx];
          C[idx] = v;
        }
      }
    }
  }
}

// ---------------- 256^2 deep-pipelined bf16 B^T GEMM (T2+T3/T4+T5) ----------------
// 512 thr = 8 waves (2M x 4N); BK=64; LDS 128KB double-buffered.
// Swizzle: 16B slot s of row r holds global k-slot (s ^ (r&7)) -- pre-swizzled
// global source keeps global_load_lds dest linear (rule #21); ds_read applies
// the same XOR -> 2 lanes/bank (conflict-free).
// Pipeline: stage(kt+1) issued at top of kt's compute; single
// __syncthreads() (vmcnt drain) per K-tile lands after ~64 MFMAs of slack.
__global__ __launch_bounds__(512, 2) void gemm256(const short* __restrict__ A,
                                                  const short* __restrict__ B,
                                                  float* __restrict__ C,
                                                  int M, int N, int K, int nMt) {
  __shared__ short lds[2][2][256 * 64];  // [buf][0=A,1=B][row*64 + k]
  const int t = threadIdx.x;
  const int lane = t & 63;
  const int w = t >> 6;
  const int wm = w >> 2, wn = w & 3;
  const int lr = lane & 15, l4 = lane >> 4;
  const int nwg = gridDim.x;
  const int chunk = nwg >> 3;
  const int wg = (blockIdx.x & 7) * chunk + (blockIdx.x >> 3);
  const int mi = wg % nMt, ni = wg / nMt;
  const size_t rowBase = (size_t)mi * 256, colBase = (size_t)ni * 256;

  // staging: 8 x 16B per thread per K-tile (A-tile 32KB + B-tile 32KB)
  const short* aSrc[4]; const short* bSrc[4];
  int ldsOff[4];
#pragma unroll
  for (int p = 0; p < 4; ++p) {
    int q = p * 512 + t;
    int row = q >> 3, s = q & 7;
    int ks = (s ^ (row & 7)) * 8;         // pre-swizzled global k offset
    aSrc[p] = A + (rowBase + row) * K + ks;
    bSrc[p] = B + (colBase + row) * K + ks;
    ldsOff[p] = q * 8;                    // linear LDS dest (shorts)
  }
  auto stage = [&](int buf, int k0) {
#pragma unroll
    for (int p = 0; p < 4; ++p)
      __builtin_amdgcn_global_load_lds(
          (__attribute__((address_space(1))) unsigned int*)(aSrc[p] + k0),
          (__attribute__((address_space(3))) unsigned int*)(&lds[buf][0][ldsOff[p]]), 16, 0, 0);
#pragma unroll
    for (int p = 0; p < 4; ++p)
      __builtin_amdgcn_global_load_lds(
          (__attribute__((address_space(1))) unsigned int*)(bSrc[p] + k0),
          (__attribute__((address_space(3))) unsigned int*)(&lds[buf][1][ldsOff[p]]), 16, 0, 0);
  };

  f32x4 acc[8][4];
#pragma unroll
  for (int i = 0; i < 8; i++)
#pragma unroll
    for (int j = 0; j < 4; j++) acc[i][j] = f32x4{0.f, 0.f, 0.f, 0.f};

  stage(0, 0);
  const int KT = K >> 6;
  for (int kt = 0; kt < KT; ++kt) {
    const int cur = kt & 1;
    __syncthreads();  // drains vmcnt(0): stage(kt) done; buf[cur^1] free
    // ---- phase 1: A rows [wm*128, +63] x full K64, all B ----
    bf16x8 a0[4][2], b0[4][2];
#pragma unroll
    for (int i = 0; i < 4; i++)
#pragma unroll
      for (int kq = 0; kq < 2; kq++) {
        int r = wm * 128 + i * 16 + lr;
        int ks = kq * 4 + l4;
        a0[i][kq] = *(const bf16x8*)&lds[cur][0][r * 64 + ((ks ^ (r & 7)) << 3)];
      }
#pragma unroll
    for (int j = 0; j < 4; j++)
#pragma unroll
      for (int kq = 0; kq < 2; kq++) {
        int r = wn * 64 + j * 16 + lr;
        int ks = kq * 4 + l4;
        b0[j][kq] = *(const bf16x8*)&lds[cur][1][r * 64 + ((ks ^ (r & 7)) << 3)];
      }
    if (kt + 1 < KT) stage(cur ^ 1, (kt + 1) << 6);
    __builtin_amdgcn_s_setprio(1);
#pragma unroll
    for (int i = 0; i < 4; i++)
#pragma unroll
      for (int j = 0; j < 4; j++)
#pragma unroll
        for (int kq = 0; kq < 2; kq++)
          acc[i][j] = __builtin_amdgcn_mfma_f32_16x16x32_bf16(a0[i][kq], b0[j][kq], acc[i][j], 0, 0, 0);
    __builtin_amdgcn_s_setprio(0);
    // ---- phase 2: A rows [wm*128+64, +63] ----
    bf16x8 a1[4][2];
#pragma unroll
    for (int i = 0; i < 4; i++)
#pragma unroll
      for (int kq = 0; kq < 2; kq++) {
        int r = wm * 128 + 64 + i * 16 + lr;
        int ks = kq * 4 + l4;
        a1[i][kq] = *(const bf16x8*)&lds[cur][0][r * 64 + ((ks ^ (r & 7)) << 3)];
      }
    __builtin_amdgcn_s_setprio(1);
#pragma unroll
    for (int i = 0; i < 4; i++)
#pragma unroll
      for (int j = 0; j < 4; j++)
#pragma unroll
        for (int kq = 0; kq < 2; kq++)
          acc[i + 4][j] = __builtin_amdgcn_mfma_f32_16x16x32_bf16(a1[i][kq], b0[j][kq], acc[i + 4][j], 0, 0, 0);
    __builtin_amdgcn_s_setprio(0);
  }
  // ---- epilogue ----
#pragma unroll
  for (int i = 0; i < 8; i++) {
#pragma unroll
    for (int j = 0; j < 4; j++) {
      size_t r0 = rowBase + wm * 128 + i * 16 + l4 * 4;
      size_t c = colBase + wn * 64 + j * 16 + lr;
#pragma unroll
      for (int rr = 0; rr < 4; rr++)
        C[(r0 + rr) * N + c] = acc[i][j][rr];
    }
  }
}

// ---------------- depthwise causal conv1d (K=4) + bias + SiLU -> bf16 ----------------
__global__ __launch_bounds__(256) void conv_silu_k(const float* __restrict__ xz,
                                                   const float* __restrict__ cw,
                                                   const float* __restrict__ cb,
                                                   short* __restrict__ xiC) {
  int idx = blockIdx.x * 256 + threadIdx.x;  // over S*DI
  int s = idx / DIc, c = idx - s * DIc;
  float acc = cb[c];
  float w0 = cw[c * 4 + 0], w1 = cw[c * 4 + 1], w2 = cw[c * 4 + 2], w3 = cw[c * 4 + 3];
  float x0 = (s >= 3) ? xz[(size_t)(s - 3) * (2 * DIc) + c] : 0.f;
  float x1 = (s >= 2) ? xz[(size_t)(s - 2) * (2 * DIc) + c] : 0.f;
  float x2 = (s >= 1) ? xz[(size_t)(s - 1) * (2 * DIc) + c] : 0.f;
  float x3 = xz[(size_t)s * (2 * DIc) + c];
  acc += w0 * x0 + w1 * x1 + w2 * x2 + w3 * x3;
  float sv = acc / (1.f + __expf(-acc));
  xiC[idx] = f2bf(sv);
}

// ---------------- scan pass 1: per-chunk (prod a, local scan); A=-exp fused ----------------
__global__ __launch_bounds__(256) void scan_pass1(const float* __restrict__ dt,
                                                  const short* __restrict__ u,
                                                  const float* __restrict__ bc,
                                                  const float* __restrict__ alog,
                                                  float* __restrict__ Ap,
                                                  float* __restrict__ Hl) {
  const int j = blockIdx.x;
  const int d = blockIdx.y * 256 + threadIdx.x;
  __shared__ float sB[LCH][Nn];
  for (int q = threadIdx.x; q < LCH * Nn; q += 256) {
    int tt = q >> 4, n = q & 15;
    sB[tt][n] = bc[(size_t)(j * LCH + tt) * 32 + n];
  }
  __syncthreads();
  float Ar[Nn], h[Nn], ap[Nn];
#pragma unroll
  for (int n = 0; n < Nn; n++) {
    Ar[n] = -__expf(alog[d * Nn + n]); h[n] = 0.f; ap[n] = 1.f;
  }
  const int t0 = j * LCH;
  for (int tt = 0; tt < LCH; tt++) {
    size_t gi = (size_t)(t0 + tt) * DIc + d;
    float dtv = dt[gi];
    float uv = bf2f(u[gi]);
    float dtu = dtv * uv;
#pragma unroll
    for (int n = 0; n < Nn; n++) {
      float a = __expf(dtv * Ar[n]);
      h[n] = a * h[n] + dtu * sB[tt][n];
      ap[n] *= a;
    }
  }
  size_t base = ((size_t)j * DIc + d) * Nn;
#pragma unroll
  for (int n = 0; n < Nn; n++) { Ap[base + n] = ap[n]; Hl[base + n] = h[n]; }
}

// ---------------- scan combine: sequential over chunks ----------------
__global__ __launch_bounds__(256) void scan_combine(const float* __restrict__ Ap,
                                                    const float* __restrict__ Hl,
                                                    float* __restrict__ Hi) {
  int idx = blockIdx.x * 256 + threadIdx.x;  // over DI*N
  float h = 0.f;
  for (int j = 0; j < NCHc; j++) {
    size_t o = (size_t)j * DIc * Nn + idx;
    Hi[o] = h;
    h = Ap[o] * h + Hl[o];
  }
}

// ---------------- scan pass 2: emit y * silu(z) as bf16; A=-exp fused ----------------
__global__ __launch_bounds__(256) void scan_pass2(const float* __restrict__ dt,
                                                  const short* __restrict__ u,
                                                  const float* __restrict__ bc,
                                                  const float* __restrict__ alog,
                                                  const float* __restrict__ Hinit,
                                                  const float* __restrict__ Dp,
                                                  const float* __restrict__ xz,
                                                  short* __restrict__ y) {
  const int j = blockIdx.x;
  const int d = blockIdx.y * 256 + threadIdx.x;
  __shared__ float sB[LCH][Nn], sC[LCH][Nn];
  for (int q = threadIdx.x; q < LCH * Nn; q += 256) {
    int tt = q >> 4, n = q & 15;
    size_t r = (size_t)(j * LCH + tt) * 32;
    sB[tt][n] = bc[r + n];
    sC[tt][n] = bc[r + 16 + n];
  }
  __syncthreads();
  float Ar[Nn], h[Nn];
  size_t hb = ((size_t)j * DIc + d) * Nn;
#pragma unroll
  for (int n = 0; n < Nn; n++) {
    Ar[n] = -__expf(alog[d * Nn + n]); h[n] = Hinit[hb + n];
  }
  float dp = Dp[d];
  const int t0 = j * LCH;
  for (int tt = 0; tt < LCH; tt++) {
    size_t gi = (size_t)(t0 + tt) * DIc + d;
    float dtv = dt[gi];
    float uv = bf2f(u[gi]);
    float dtu = dtv * uv;
    float yv = dp * uv;
#pragma unroll
    for (int n = 0; n < Nn; n++) {
      float a = __expf(dtv * Ar[n]);
      h[n] = a * h[n] + dtu * sB[tt][n];
      yv += h[n] * sC[tt][n];
    }
    float zv = xz[(size_t)(t0 + tt) * (2 * DIc) + DIc + d];
    float sz = zv / (1.f + __expf(-zv));
    y[gi] = f2bf(yv * sz);
  }
}

// ---------------- host orchestration ----------------
extern "C" void kernel_launch(void* const* d_in, const int* in_sizes, int n_in,
                              void* d_out, int out_size, void* d_ws, size_t ws_size,
                              hipStream_t stream) {
  (void)in_sizes; (void)n_in; (void)out_size; (void)ws_size;
  const int* ids = (const int*)d_in[0];
  const float* emb = (const float*)d_in[1];
  const float* in_proj_w = (const float*)d_in[2];
  const float* conv_w = (const float*)d_in[3];
  const float* conv_b = (const float*)d_in[4];
  const float* x_proj_w = (const float*)d_in[5];
  const float* dt_proj_w = (const float*)d_in[6];
  const float* dt_proj_b = (const float*)d_in[7];
  const float* A_log = (const float*)d_in[8];
  const float* D_param = (const float*)d_in[9];
  const float* out_proj_w = (const float*)d_in[10];
  const float* norm_w = (const float*)d_in[11];
  const float* norm_f_w = (const float*)d_in[12];
  const float* lm_head_w = (const float*)d_in[13];
  float* logits = (float*)d_out;

  // lm_head-phase-live buffers in d_ws; dead-before-final-GEMM scratch in d_out.
  char* ws = (char*)d_ws;
  size_t woff = 0;
  auto walloc = [&](size_t bytes) { void* p = ws + woff; woff += (bytes + 255) & ~(size_t)255; return p; };
  float* x     = (float*)walloc((size_t)Ss * Dd * 4);
  short* xfbf  = (short*)walloc((size_t)Ss * Dd * 2);
  short* w_lm  = (short*)walloc((size_t)Vv * Dd * 2);

  char* sc = (char*)d_out;
  size_t soff = 0;
  auto salloc = [&](size_t bytes) { void* p = sc + soff; soff += (bytes + 255) & ~(size_t)255; return p; };
  float* xz   = (float*)salloc((size_t)Ss * 2 * DIc * 4);
  float* dtb  = (float*)salloc((size_t)Ss * DIc * 4);
  float* bc   = (float*)salloc((size_t)Ss * 32 * 4);
  float* Ap   = (float*)salloc((size_t)NCHc * DIc * Nn * 4);
  float* Hl   = (float*)salloc((size_t)NCHc * DIc * Nn * 4);
  float* Hi   = (float*)salloc((size_t)NCHc * DIc * Nn * 4);
  short* hbf  = (short*)salloc((size_t)Ss * Dd * 2);
  short* xiC  = (short*)salloc((size_t)Ss * DIc * 2);
  short* ybf  = (short*)salloc((size_t)Ss * DIc * 2);
  short* w_in = (short*)salloc((size_t)NLay * 2 * DIc * Dd * 2);
  short* w_cat= (short*)salloc((size_t)NLay * CATR * DIc * 2);
  short* w_out= (short*)salloc((size_t)NLay * Dd * DIc * 2);

  // one batched weight-convert launch
  CvtBatch cb2{};
  unsigned tot = 0;
  auto addseg = [&](int i, const float* s, short* d, size_t n) {
    cb2.seg[i].s = s; cb2.seg[i].d = d; cb2.seg[i].n4 = (unsigned)(n / 4);
    tot += (unsigned)(n / 4);
  };
  addseg(0, in_proj_w, w_in, (size_t)NLay * 2 * DIc * Dd);
  addseg(1, out_proj_w, w_out, (size_t)NLay * Dd * DIc);
  addseg(2, lm_head_w, w_lm, (size_t)Vv * Dd);
  addseg(3, dt_proj_w, w_cat, (size_t)DIc * DIc);
  addseg(4, x_proj_w, w_cat + (size_t)DIc * DIc, (size_t)2 * Nn * DIc);
  addseg(5, dt_proj_w + (size_t)DIc * DIc, w_cat + (size_t)CATR * DIc, (size_t)DIc * DIc);
  addseg(6, x_proj_w + (size_t)2 * Nn * DIc,
         w_cat + (size_t)CATR * DIc + (size_t)DIc * DIc, (size_t)2 * Nn * DIc);
  cb2.tot4 = tot;
  cvt_all_k<<<dim3(4096), dim3(256), 0, stream>>>(cb2);

  embed_k<<<dim3(Ss), dim3(256), 0, stream>>>(ids, emb, x);

  for (int l = 0; l < NLay; l++) {
    rmsnorm_k<<<dim3(Ss), dim3(256), 0, stream>>>(x, norm_w + (size_t)l * Dd, hbf);
    gemm_bt<128, 128, 2, 2, false, false><<<dim3(16 * 32), dim3(256), 0, stream>>>(
        hbf, w_in + (size_t)l * 2 * DIc * Dd, xz, nullptr, nullptr, Ss, 2 * DIc, Dd, 16);
    conv_silu_k<<<dim3(Ss * DIc / 256), dim3(256), 0, stream>>>(
        xz, conv_w + (size_t)l * DIc * Kc, conv_b + (size_t)l * DIc, xiC);
    gemm_bt<128, 128, 2, 2, false, true><<<dim3(16 * 17), dim3(256), 0, stream>>>(
        xiC, w_cat + (size_t)l * CATR * DIc, dtb, dt_proj_b + (size_t)l * DIc, bc,
        Ss, CATR, DIc, 16);
    scan_pass1<<<dim3(NCHc, DIc / 256), dim3(256), 0, stream>>>(
        dtb, xiC, bc, A_log + (size_t)l * DIc * Nn, Ap, Hl);
    scan_combine<<<dim3(DIc * Nn / 256), dim3(256), 0, stream>>>(Ap, Hl, Hi);
    scan_pass2<<<dim3(NCHc, DIc / 256), dim3(256), 0, stream>>>(
        dtb, xiC, bc, A_log + (size_t)l * DIc * Nn, Hi,
        D_param + (size_t)l * DIc, xz, ybf);
    gemm_bt<128, 128, 2, 2, true, false><<<dim3(16 * 8), dim3(256), 0, stream>>>(
        ybf, w_out + (size_t)l * Dd * DIc, x, x, nullptr, Ss, Dd, DIc, 16);
  }

  rmsnorm_k<<<dim3(Ss), dim3(256), 0, stream>>>(x, norm_f_w, xfbf);
  // lm_head on the deep-pipelined 256^2 kernel: grid 8*125=1000 (nwg%8==0)
  gemm256<<<dim3(8 * 125), dim3(512), 0, stream>>>(xfbf, w_lm, logits, Ss, Vv, Dd, 8);
}